// Round 4
// baseline (121.483 us; speedup 1.0000x reference)
//
#include <hip/hip_runtime.h>

typedef __attribute__((ext_vector_type(8))) short short8;
typedef __attribute__((ext_vector_type(4))) float f32x4;
typedef unsigned short ushort_t;

#define B_ 4
#define N_ 4096
#define E_ 256
#define D_ 64
#define S2LOG 0.1803368801111204f   // (1/sqrt(64)) * log2(e)
#define BIGNEG (-1e30f)
#define THR 8.0f                    // defer-max threshold (log2 units): p <= 256

static __device__ __forceinline__ unsigned short f2bf(float f) {
  union { float f; unsigned int u; } v; v.f = f;
  return (unsigned short)((v.u + 0x7fffu + ((v.u >> 16) & 1u)) >> 16);  // RNE
}
static __device__ __forceinline__ float bf2f(unsigned short h) {
  union { unsigned u; float f; } c; c.u = ((unsigned)h) << 16; return c.f;
}
static __device__ __forceinline__ float exp2_fast(float x) {
  float r; asm("v_exp_f32 %0, %1" : "=v"(r) : "v"(x)); return r;
}
static __device__ __forceinline__ unsigned cvt_pk_bf16(float lo, float hi) {
  unsigned r; asm("v_cvt_pk_bf16_f32 %0, %1, %2" : "=v"(r) : "v"(lo), "v"(hi));
  return r;
}

// ---------------------------------------------------------------------------
// Projection: out = X @ W^T  (X:[B*N,256] f32, W:[64,256] f32) -> bf16
// p=0: q [B*N][64] (+ mask->bias fold); p=1: k [B*N][64]; p=2: vT [B][64][N]
// ---------------------------------------------------------------------------
__global__ __launch_bounds__(256) void proj_kernel(
    const float* __restrict__ Qv, const float* __restrict__ Kv,
    const float* __restrict__ Vv, const float* __restrict__ Wq,
    const float* __restrict__ Wk, const float* __restrict__ Wv,
    const int* __restrict__ mask,
    unsigned short* __restrict__ qo, unsigned short* __restrict__ ko,
    unsigned short* __restrict__ vto, float* __restrict__ biasf)
{
  const int p  = blockIdx.y;
  const int rb = blockIdx.x;
  const int t  = threadIdx.x;

  __align__(16) __shared__ unsigned short Xl[64 * 264];
  __align__(16) __shared__ unsigned short Wl[64 * 264];

  const float* xsrc = (p == 0 ? Qv : (p == 1 ? Kv : Vv)) + (size_t)rb * 64 * E_;
  const float* wsrc = (p == 0 ? Wq : (p == 1 ? Wk : Wv));

  if (p == 0 && t < 64) biasf[rb * 64 + t] = mask[rb * 64 + t] ? 0.f : BIGNEG;

  #pragma unroll
  for (int it = 0; it < 8; ++it) {
    int idx = it * 2048 + t * 8;
    int row = idx >> 8, col = idx & 255;
    float4 a0 = *(const float4*)(xsrc + idx);
    float4 a1 = *(const float4*)(xsrc + idx + 4);
    uint4 wx;
    wx.x = (unsigned)f2bf(a0.x) | ((unsigned)f2bf(a0.y) << 16);
    wx.y = (unsigned)f2bf(a0.z) | ((unsigned)f2bf(a0.w) << 16);
    wx.z = (unsigned)f2bf(a1.x) | ((unsigned)f2bf(a1.y) << 16);
    wx.w = (unsigned)f2bf(a1.z) | ((unsigned)f2bf(a1.w) << 16);
    *(uint4*)&Xl[row * 264 + col] = wx;
    float4 b0 = *(const float4*)(wsrc + idx);
    float4 b1 = *(const float4*)(wsrc + idx + 4);
    uint4 ww;
    ww.x = (unsigned)f2bf(b0.x) | ((unsigned)f2bf(b0.y) << 16);
    ww.y = (unsigned)f2bf(b0.z) | ((unsigned)f2bf(b0.w) << 16);
    ww.z = (unsigned)f2bf(b1.x) | ((unsigned)f2bf(b1.y) << 16);
    ww.w = (unsigned)f2bf(b1.z) | ((unsigned)f2bf(b1.w) << 16);
    *(uint4*)&Wl[row * 264 + col] = ww;
  }
  __syncthreads();

  const int wave = t >> 6, lane = t & 63, g = lane >> 4, lq = lane & 15;
  const unsigned short* TA = (p == 2) ? Wl : Xl;
  const unsigned short* TB = (p == 2) ? Xl : Wl;

  f32x4 acc0 = {0.f,0.f,0.f,0.f}, acc1 = acc0, acc2 = acc0, acc3 = acc0;
  #pragma unroll
  for (int kc = 0; kc < 8; ++kc) {
    short8 af = *(const short8*)&TA[(wave * 16 + lq) * 264 + kc * 32 + g * 8];
    short8 b0 = *(const short8*)&TB[(0 * 16 + lq) * 264 + kc * 32 + g * 8];
    acc0 = __builtin_amdgcn_mfma_f32_16x16x32_bf16(af, b0, acc0, 0, 0, 0);
    short8 b1 = *(const short8*)&TB[(1 * 16 + lq) * 264 + kc * 32 + g * 8];
    acc1 = __builtin_amdgcn_mfma_f32_16x16x32_bf16(af, b1, acc1, 0, 0, 0);
    short8 b2 = *(const short8*)&TB[(2 * 16 + lq) * 264 + kc * 32 + g * 8];
    acc2 = __builtin_amdgcn_mfma_f32_16x16x32_bf16(af, b2, acc2, 0, 0, 0);
    short8 b3 = *(const short8*)&TB[(3 * 16 + lq) * 264 + kc * 32 + g * 8];
    acc3 = __builtin_amdgcn_mfma_f32_16x16x32_bf16(af, b3, acc3, 0, 0, 0);
  }

  if (p < 2) {
    unsigned short* dst = (p == 0 ? qo : ko);
    #pragma unroll
    for (int c = 0; c < 4; ++c) {
      const f32x4 ac = (c == 0 ? acc0 : c == 1 ? acc1 : c == 2 ? acc2 : acc3);
      #pragma unroll
      for (int r = 0; r < 4; ++r) {
        int n = rb * 64 + wave * 16 + g * 4 + r;
        dst[(size_t)n * D_ + c * 16 + lq] = f2bf(ac[r]);
      }
    }
  } else {
    int bb = (rb * 64) >> 12;
    #pragma unroll
    for (int c = 0; c < 4; ++c) {
      const f32x4 ac = (c == 0 ? acc0 : c == 1 ? acc1 : c == 2 ? acc2 : acc3);
      #pragma unroll
      for (int r = 0; r < 4; ++r) {
        int d = wave * 16 + g * 4 + r;
        int n = (rb * 64 + c * 16 + lq) & (N_ - 1);
        vto[((size_t)bb * D_ + d) * N_ + n] = f2bf(ac[r]);
      }
    }
  }
}

// ---------------------------------------------------------------------------
// vmean[b][d] = (1/N) sum_n v[b][n][d].  64 blocks x 4 waves; one wave per
// (b,d) row; coalesced short8 reads + full-wave shfl reduce.
// ---------------------------------------------------------------------------
__global__ __launch_bounds__(256) void vmean_kernel(
    const ushort_t* __restrict__ vt, float* __restrict__ vmean)
{
  const int t = threadIdx.x, wave = t >> 6, lane = t & 63;
  const int idx = blockIdx.x * 4 + wave;          // (b*64 + d) in [0,256)
  const ushort_t* row = vt + (size_t)idx * N_;
  float s = 0.f;
  #pragma unroll
  for (int i = 0; i < 8; ++i) {
    short8 v = *(const short8*)&row[(i * 64 + lane) * 8];
    #pragma unroll
    for (int j = 0; j < 8; ++j) s += bf2f((unsigned short)v[j]);
  }
  #pragma unroll
  for (int off = 1; off < 64; off <<= 1) s += __shfl_xor(s, off, 64);
  if (lane == 0) vmean[idx] = s * (1.f / N_);
}

// ---------------------------------------------------------------------------
// Flash attention, KV-split. 8 waves x 16 q = 128 q/block; key tile 64;
// single-buffered swizzled K/V LDS + reg prefetch (T14); row-sum l via
// 2 extra MFMAs against a constant ones B-operand (kills 15 adds + 2 shfl).
// LDS = 32 KB -> 4 blocks/CU; launch_bounds(512,8) targets 32 waves/CU.
// ---------------------------------------------------------------------------
__global__ __launch_bounds__(512, 8) void attn4_kernel(
    const ushort_t* __restrict__ q, const ushort_t* __restrict__ kk,
    const ushort_t* __restrict__ vt, const float* __restrict__ biasf,
    float* __restrict__ op0, float* __restrict__ opws,
    float* __restrict__ mlbuf, int nsplit)
{
  const int b = blockIdx.y, qt = blockIdx.x, sp = blockIdx.z;
  const int t = threadIdx.x;
  const int wave = t >> 6, lane = t & 63, g = lane >> 4, lq = lane & 15;

  const int TT = N_ / 64;
  const int tile_lo = (sp * TT) / nsplit;
  const int tile_hi = ((sp + 1) * TT) / nsplit;
  const int nit = tile_hi - tile_lo;

  __align__(16) __shared__ ushort_t Kt[64 * 64];      // [key][d], 16B-chunk XOR swz
  __align__(16) __shared__ ushort_t Vt[64 * 64];      // [d][key], 16B-chunk XOR swz
  __align__(16) __shared__ ushort_t Pl[8][16 * 64];   // per-wave P, XOR swz

  const int qbase = qt * 128 + wave * 16;
  const int qrow_b = qbase + lq;
  const size_t qoff = (size_t)(b * N_ + qrow_b) * D_;
  short8 qf0 = *(const short8*)&q[qoff + g * 8];
  short8 qf1 = *(const short8*)&q[qoff + 32 + g * 8];
  const float* biasb = biasf + b * N_;

  const short8 ones = {0x3F80, 0x3F80, 0x3F80, 0x3F80,
                       0x3F80, 0x3F80, 0x3F80, 0x3F80};   // bf16 1.0 x8

  float m = 0.f;                    // finite init; defer-max bounds p <= 2^THR
  f32x4 o[5];                       // o[0..3] = O' (64 d), o[4] = l column
  #pragma unroll
  for (int i = 0; i < 5; ++i) o[i] = f32x4{0.f, 0.f, 0.f, 0.f};

  const int r_ = t >> 3, j_ = t & 7;    // 512 threads stage 64x64 in one pass
  uint4 kreg, vreg;

  auto load_tile = [&](int tile) {
    const int jb = (tile_lo + tile) * 64;
    kreg = *(const uint4*)&kk[(size_t)(b * N_ + jb + r_) * D_ + j_ * 8];
    vreg = *(const uint4*)&vt[((size_t)b * D_ + r_) * N_ + jb + j_ * 8];
  };
  auto write_tile = [&]() {
    *(uint4*)&Kt[r_ * 64 + ((j_ ^ (r_ & 7)) * 8)] = kreg;
    *(uint4*)&Vt[r_ * 64 + ((j_ ^ (r_ & 7)) * 8)] = vreg;
  };

  load_tile(0);
  write_tile();
  if (nit > 1) load_tile(1);
  __syncthreads();

  for (int it = 0; it < nit; ++it) {
    const int jb = (tile_lo + it) * 64;

    // bias for this tile's 16 keys/lane (L1-hot, broadcast)
    float4 bf0 = *(const float4*)&biasb[jb + 0 * 16 + 4 * g];
    float4 bf1 = *(const float4*)&biasb[jb + 1 * 16 + 4 * g];
    float4 bf2 = *(const float4*)&biasb[jb + 2 * 16 + 4 * g];
    float4 bf3 = *(const float4*)&biasb[jb + 3 * 16 + 4 * g];

    // ---- QK^T (swapped: C rows = keys, cols = q) ----
    f32x4 st[4];
    #pragma unroll
    for (int kc = 0; kc < 4; ++kc) st[kc] = f32x4{0.f, 0.f, 0.f, 0.f};
    __builtin_amdgcn_s_setprio(1);
    #pragma unroll
    for (int kc = 0; kc < 4; ++kc) {
      const int row = kc * 16 + lq, sw = row & 7;
      short8 a0 = *(const short8*)&Kt[row * 64 + ((g ^ sw) * 8)];
      st[kc] = __builtin_amdgcn_mfma_f32_16x16x32_bf16(a0, qf0, st[kc], 0, 0, 0);
      short8 a1 = *(const short8*)&Kt[row * 64 + (((4 + g) ^ sw) * 8)];
      st[kc] = __builtin_amdgcn_mfma_f32_16x16x32_bf16(a1, qf1, st[kc], 0, 0, 0);
    }
    __builtin_amdgcn_s_setprio(0);

    // ---- scores in log2 domain ----
    float sv[16];
    #pragma unroll
    for (int kc = 0; kc < 4; ++kc) {
      const float4 bf = (kc == 0 ? bf0 : kc == 1 ? bf1 : kc == 2 ? bf2 : bf3);
      sv[kc * 4 + 0] = fmaf(st[kc][0], S2LOG, bf.x);
      sv[kc * 4 + 1] = fmaf(st[kc][1], S2LOG, bf.y);
      sv[kc * 4 + 2] = fmaf(st[kc][2], S2LOG, bf.z);
      sv[kc * 4 + 3] = fmaf(st[kc][3], S2LOG, bf.w);
    }
    if ((jb >> 6) == (qbase >> 6)) {       // wave-uniform diagonal tile
      const int dref = qrow_b - jb - 4 * g;
      #pragma unroll
      for (int kc = 0; kc < 4; ++kc)
        #pragma unroll
        for (int r = 0; r < 4; ++r)
          sv[kc * 4 + r] = (16 * kc + r == dref) ? BIGNEG : sv[kc * 4 + r];
    }

    // ---- row max ----
    float a0m = fmaxf(fmaxf(sv[0], sv[1]), sv[2]);
    float a1m = fmaxf(fmaxf(sv[3], sv[4]), sv[5]);
    float a2m = fmaxf(fmaxf(sv[6], sv[7]), sv[8]);
    float a3m = fmaxf(fmaxf(sv[9], sv[10]), sv[11]);
    float a4m = fmaxf(fmaxf(sv[12], sv[13]), sv[14]);
    float b0m = fmaxf(fmaxf(a0m, a1m), a2m);
    float b1m = fmaxf(fmaxf(a3m, a4m), sv[15]);
    float tm = fmaxf(b0m, b1m);
    tm = fmaxf(tm, __shfl_xor(tm, 16, 64));
    tm = fmaxf(tm, __shfl_xor(tm, 32, 64));

    // ---- defer-max rescale (rare) ----
    if (!__all(tm - m <= THR)) {
      const float mnew = fmaxf(m, tm);
      const float corr = exp2_fast(m - mnew);
      const float c0 = __shfl(corr, g * 4 + 0, 64);
      const float c1 = __shfl(corr, g * 4 + 1, 64);
      const float c2 = __shfl(corr, g * 4 + 2, 64);
      const float c3 = __shfl(corr, g * 4 + 3, 64);
      #pragma unroll
      for (int dc = 0; dc < 5; ++dc) {
        o[dc][0] *= c0; o[dc][1] *= c1; o[dc][2] *= c2; o[dc][3] *= c3;
      }
      m = mnew;
    }

    // ---- P = exp2(sv - m), pack bf16 ----
    unsigned pw[8];
    #pragma unroll
    for (int h = 0; h < 8; ++h) {
      float pa = exp2_fast(sv[2 * h] - m);
      float pb = exp2_fast(sv[2 * h + 1] - m);
      pw[h] = cvt_pk_bf16(pa, pb);
    }

    // ---- P bounce to per-wave swizzled LDS ----
    #pragma unroll
    for (int kc = 0; kc < 4; ++kc) {
      uint2 w; w.x = pw[kc * 2]; w.y = pw[kc * 2 + 1];
      const int c16 = 2 * kc + (g >> 1);
      *(uint2*)&Pl[wave][lq * 64 + ((c16 ^ (lq & 7)) << 3) + ((g & 1) << 2)] = w;
    }
    asm volatile("s_waitcnt lgkmcnt(0)" ::: "memory");
    __builtin_amdgcn_sched_barrier(0);

    // ---- PV + ones-column (row-sum l) ----
    short8 pf0 = *(const short8*)&Pl[wave][lq * 64 + ((g ^ (lq & 7)) << 3)];
    short8 pf1 = *(const short8*)&Pl[wave][lq * 64 + (((4 + g) ^ (lq & 7)) << 3)];
    __builtin_amdgcn_s_setprio(1);
    #pragma unroll
    for (int dc = 0; dc < 4; ++dc) {
      const int row = dc * 16 + lq, sw = row & 7;
      short8 vv0 = *(const short8*)&Vt[row * 64 + ((g ^ sw) * 8)];
      o[dc] = __builtin_amdgcn_mfma_f32_16x16x32_bf16(pf0, vv0, o[dc], 0, 0, 0);
      short8 vv1 = *(const short8*)&Vt[row * 64 + (((4 + g) ^ sw) * 8)];
      o[dc] = __builtin_amdgcn_mfma_f32_16x16x32_bf16(pf1, vv1, o[dc], 0, 0, 0);
    }
    o[4] = __builtin_amdgcn_mfma_f32_16x16x32_bf16(pf0, ones, o[4], 0, 0, 0);
    o[4] = __builtin_amdgcn_mfma_f32_16x16x32_bf16(pf1, ones, o[4], 0, 0, 0);
    __builtin_amdgcn_s_setprio(0);

    // ---- stage next tile (single buffer: 2 barriers) ----
    if (it + 1 < nit) {
      __syncthreads();                 // all waves done reading this tile
      write_tile();
      if (it + 2 < nit) load_tile(it + 2);
      __syncthreads();                 // writes visible
    }
  }

  // ---- epilogue: unnormalized O' + (m, l) ----
  float* obase = (sp == 0 ? op0 : opws + (size_t)(sp - 1) * (B_ * N_) * D_)
               + ((size_t)(b * N_) + qbase) * D_;
  #pragma unroll
  for (int dc = 0; dc < 4; ++dc) {
    #pragma unroll
    for (int r = 0; r < 4; ++r)
      obase[(size_t)(g * 4 + r) * D_ + dc * 16 + lq] = o[dc][r];
  }
  float* mlb = mlbuf + (size_t)sp * (B_ * N_) * 2 + (size_t)(b * N_) * 2;
  if (g == 0) mlb[(qbase % N_ + lq) * 2 + 0] = m;          // m at q = lq
  if (lq == 0) {
    #pragma unroll
    for (int r = 0; r < 4; ++r)
      mlb[(qbase % N_ + 4 * g + r) * 2 + 1] = o[4][r];     // l at q = 4g + r
  }
}

// ---------------------------------------------------------------------------
// Merge splits; dead q-rows get the reference's uniform mean over all V.
// ---------------------------------------------------------------------------
__global__ __launch_bounds__(256) void merge_kernel(
    const float* __restrict__ op0, const float* __restrict__ opws,
    const float* __restrict__ mlbuf, const int* __restrict__ mask,
    const float* __restrict__ vmean, float* __restrict__ out, int nsplit)
{
  const int t = threadIdx.x;
  const int qrow = blockIdx.x * 16 + (t >> 4);
  const int d = (t & 15) * 4;
  const int b = qrow >> 12;

  if (!mask[qrow]) {
    *(float4*)&out[(size_t)qrow * D_ + d] = *(const float4*)&vmean[b * D_ + d];
    return;
  }

  float M = -INFINITY;
  for (int s = 0; s < nsplit; ++s)
    M = fmaxf(M, mlbuf[((size_t)s * (B_ * N_) + qrow) * 2]);

  float L = 0.f;
  float ax = 0.f, ay = 0.f, az = 0.f, aw = 0.f;
  for (int s = 0; s < nsplit; ++s) {
    const float* mlp = &mlbuf[((size_t)s * (B_ * N_) + qrow) * 2];
    const float w = exp2_fast(mlp[0] - M);
    L += mlp[1] * w;
    const float* ob = (s == 0) ? op0 : opws + (size_t)(s - 1) * (B_ * N_) * D_;
    float4 ov = *(const float4*)&ob[(size_t)qrow * D_ + d];
    ax += ov.x * w; ay += ov.y * w; az += ov.z * w; aw += ov.w * w;
  }
  const float inv = 1.f / L;
  float4 res; res.x = ax * inv; res.y = ay * inv; res.z = az * inv; res.w = aw * inv;
  *(float4*)&out[(size_t)qrow * D_ + d] = res;
}

// ---------------------------------------------------------------------------
extern "C" void kernel_launch(void* const* d_in, const int* in_sizes, int n_in,
                              void* d_out, int out_size, void* d_ws, size_t ws_size,
                              hipStream_t stream) {
  (void)in_sizes; (void)n_in; (void)out_size;
  const float* Qv = (const float*)d_in[0];
  const float* Kv = (const float*)d_in[1];
  const float* Vv = (const float*)d_in[2];
  const int* mask = (const int*)d_in[3];
  const float* Wq = (const float*)d_in[4];
  const float* Wk = (const float*)d_in[5];
  const float* Wv = (const float*)d_in[6];
  float* out = (float*)d_out;

  ushort_t* qb_ = (ushort_t*)d_ws;                         // [B*N][64] bf16
  ushort_t* kb_ = qb_ + (size_t)B_ * N_ * D_;              // [B*N][64] bf16
  ushort_t* vtb = kb_ + (size_t)B_ * N_ * D_;              // [B][64][N] bf16
  float* biasf  = (float*)(vtb + (size_t)B_ * N_ * D_);    // [B*N] f32
  float* vmean  = biasf + (size_t)B_ * N_;                 // [B][64] f32
  float* mlbuf  = vmean + (size_t)B_ * D_;                 // [8][B*N][2] f32 max
  float* opws   = mlbuf + (size_t)8 * B_ * N_ * 2;         // (nsplit-1) x [B*N][64] f32
  const size_t fixed_bytes = (size_t)((char*)opws - (char*)d_ws);
  const size_t slice_bytes = (size_t)B_ * N_ * D_ * sizeof(float);

  int nsplit = 1;
  if      (ws_size >= fixed_bytes + 7 * slice_bytes) nsplit = 8;
  else if (ws_size >= fixed_bytes + 3 * slice_bytes) nsplit = 4;
  else if (ws_size >= fixed_bytes + 1 * slice_bytes) nsplit = 2;

  proj_kernel<<<dim3(256, 3), dim3(256), 0, stream>>>(
      Qv, Kv, Vv, Wq, Wk, Wv, mask, qb_, kb_, vtb, biasf);
  vmean_kernel<<<dim3(64), dim3(256), 0, stream>>>(vtb, vmean);
  attn4_kernel<<<dim3(N_ / 128, B_, nsplit), dim3(512), 0, stream>>>(
      qb_, kb_, vtb, biasf, out, opws, mlbuf, nsplit);
  merge_kernel<<<dim3(B_ * N_ / 16), dim3(256), 0, stream>>>(
      out, opws, mlbuf, mask, vmean, out, nsplit);
}

// Round 5
// 102.613 us; speedup vs baseline: 1.1839x; 1.1839x over previous
//
#include <hip/hip_runtime.h>

typedef __attribute__((ext_vector_type(8))) short short8;
typedef __attribute__((ext_vector_type(4))) float f32x4;
typedef unsigned short ushort_t;

#define B_ 4
#define N_ 4096
#define E_ 256
#define D_ 64
#define S2LOG 0.1803368801111204f   // (1/sqrt(64)) * log2(e)
#define BIGNEG (-1e30f)
#define THR 8.0f                    // defer-max threshold (log2 units): p <= 256

static __device__ __forceinline__ unsigned short f2bf(float f) {
  union { float f; unsigned int u; } v; v.f = f;
  return (unsigned short)((v.u + 0x7fffu + ((v.u >> 16) & 1u)) >> 16);  // RNE
}
static __device__ __forceinline__ float bf2f(unsigned short h) {
  union { unsigned u; float f; } c; c.u = ((unsigned)h) << 16; return c.f;
}
static __device__ __forceinline__ float exp2_fast(float x) {
  float r; asm("v_exp_f32 %0, %1" : "=v"(r) : "v"(x)); return r;
}
static __device__ __forceinline__ unsigned cvt_pk_bf16(float lo, float hi) {
  unsigned r; asm("v_cvt_pk_bf16_f32 %0, %1, %2" : "=v"(r) : "v"(lo), "v"(hi));
  return r;
}

// ---------------------------------------------------------------------------
// Projection: out = X @ W^T  (X:[B*N,256] f32, W:[64,256] f32) -> bf16
// p=0: q [B*N][64] (+ mask->bias fold); p=1: k [B*N][64]; p=2: vT [B][64][N]
// ---------------------------------------------------------------------------
__global__ __launch_bounds__(256) void proj_kernel(
    const float* __restrict__ Qv, const float* __restrict__ Kv,
    const float* __restrict__ Vv, const float* __restrict__ Wq,
    const float* __restrict__ Wk, const float* __restrict__ Wv,
    const int* __restrict__ mask,
    unsigned short* __restrict__ qo, unsigned short* __restrict__ ko,
    unsigned short* __restrict__ vto, float* __restrict__ biasf)
{
  const int p  = blockIdx.y;
  const int rb = blockIdx.x;
  const int t  = threadIdx.x;

  __align__(16) __shared__ unsigned short Xl[64 * 264];
  __align__(16) __shared__ unsigned short Wl[64 * 264];

  const float* xsrc = (p == 0 ? Qv : (p == 1 ? Kv : Vv)) + (size_t)rb * 64 * E_;
  const float* wsrc = (p == 0 ? Wq : (p == 1 ? Wk : Wv));

  if (p == 0 && t < 64) biasf[rb * 64 + t] = mask[rb * 64 + t] ? 0.f : BIGNEG;

  #pragma unroll
  for (int it = 0; it < 8; ++it) {
    int idx = it * 2048 + t * 8;
    int row = idx >> 8, col = idx & 255;
    float4 a0 = *(const float4*)(xsrc + idx);
    float4 a1 = *(const float4*)(xsrc + idx + 4);
    uint4 wx;
    wx.x = (unsigned)f2bf(a0.x) | ((unsigned)f2bf(a0.y) << 16);
    wx.y = (unsigned)f2bf(a0.z) | ((unsigned)f2bf(a0.w) << 16);
    wx.z = (unsigned)f2bf(a1.x) | ((unsigned)f2bf(a1.y) << 16);
    wx.w = (unsigned)f2bf(a1.z) | ((unsigned)f2bf(a1.w) << 16);
    *(uint4*)&Xl[row * 264 + col] = wx;
    float4 b0 = *(const float4*)(wsrc + idx);
    float4 b1 = *(const float4*)(wsrc + idx + 4);
    uint4 ww;
    ww.x = (unsigned)f2bf(b0.x) | ((unsigned)f2bf(b0.y) << 16);
    ww.y = (unsigned)f2bf(b0.z) | ((unsigned)f2bf(b0.w) << 16);
    ww.z = (unsigned)f2bf(b1.x) | ((unsigned)f2bf(b1.y) << 16);
    ww.w = (unsigned)f2bf(b1.z) | ((unsigned)f2bf(b1.w) << 16);
    *(uint4*)&Wl[row * 264 + col] = ww;
  }
  __syncthreads();

  const int wave = t >> 6, lane = t & 63, g = lane >> 4, lq = lane & 15;
  const unsigned short* TA = (p == 2) ? Wl : Xl;
  const unsigned short* TB = (p == 2) ? Xl : Wl;

  f32x4 acc0 = {0.f,0.f,0.f,0.f}, acc1 = acc0, acc2 = acc0, acc3 = acc0;
  #pragma unroll
  for (int kc = 0; kc < 8; ++kc) {
    short8 af = *(const short8*)&TA[(wave * 16 + lq) * 264 + kc * 32 + g * 8];
    short8 b0 = *(const short8*)&TB[(0 * 16 + lq) * 264 + kc * 32 + g * 8];
    acc0 = __builtin_amdgcn_mfma_f32_16x16x32_bf16(af, b0, acc0, 0, 0, 0);
    short8 b1 = *(const short8*)&TB[(1 * 16 + lq) * 264 + kc * 32 + g * 8];
    acc1 = __builtin_amdgcn_mfma_f32_16x16x32_bf16(af, b1, acc1, 0, 0, 0);
    short8 b2 = *(const short8*)&TB[(2 * 16 + lq) * 264 + kc * 32 + g * 8];
    acc2 = __builtin_amdgcn_mfma_f32_16x16x32_bf16(af, b2, acc2, 0, 0, 0);
    short8 b3 = *(const short8*)&TB[(3 * 16 + lq) * 264 + kc * 32 + g * 8];
    acc3 = __builtin_amdgcn_mfma_f32_16x16x32_bf16(af, b3, acc3, 0, 0, 0);
  }

  if (p < 2) {
    unsigned short* dst = (p == 0 ? qo : ko);
    #pragma unroll
    for (int c = 0; c < 4; ++c) {
      const f32x4 ac = (c == 0 ? acc0 : c == 1 ? acc1 : c == 2 ? acc2 : acc3);
      #pragma unroll
      for (int r = 0; r < 4; ++r) {
        int n = rb * 64 + wave * 16 + g * 4 + r;
        dst[(size_t)n * D_ + c * 16 + lq] = f2bf(ac[r]);
      }
    }
  } else {
    int bb = (rb * 64) >> 12;
    #pragma unroll
    for (int c = 0; c < 4; ++c) {
      const f32x4 ac = (c == 0 ? acc0 : c == 1 ? acc1 : c == 2 ? acc2 : acc3);
      #pragma unroll
      for (int r = 0; r < 4; ++r) {
        int d = wave * 16 + g * 4 + r;
        int n = (rb * 64 + c * 16 + lq) & (N_ - 1);
        vto[((size_t)bb * D_ + d) * N_ + n] = f2bf(ac[r]);
      }
    }
  }
}

// ---------------------------------------------------------------------------
// vmean[b][d] = (1/N) sum_n v[b][n][d].  64 blocks x 4 waves, coalesced.
// ---------------------------------------------------------------------------
__global__ __launch_bounds__(256) void vmean_kernel(
    const ushort_t* __restrict__ vt, float* __restrict__ vmean)
{
  const int t = threadIdx.x, wave = t >> 6, lane = t & 63;
  const int idx = blockIdx.x * 4 + wave;          // (b*64 + d) in [0,256)
  const ushort_t* row = vt + (size_t)idx * N_;
  float s = 0.f;
  #pragma unroll
  for (int i = 0; i < 8; ++i) {
    short8 v = *(const short8*)&row[(i * 64 + lane) * 8];
    #pragma unroll
    for (int j = 0; j < 8; ++j) s += bf2f((unsigned short)v[j]);
  }
  #pragma unroll
  for (int off = 1; off < 64; off <<= 1) s += __shfl_xor(s, off, 64);
  if (lane == 0) vmean[idx] = s * (1.f / N_);
}

// ---------------------------------------------------------------------------
// Flash attention, KV-split. 4 waves x 32 q = 128 q/block; key tile 64;
// double-buffered swizzled K/V LDS (1 barrier/tile); each K/V ds_read feeds
// TWO 16-q column blocks (halves LDS traffic vs 16q/wave); row-sum l via
// MFMA against ones; P bounce via per-wave 80B-stride buffer (2-way banks).
// LDS = 37.9 KB -> 4 blocks/CU; launch_bounds(256,4) caps VGPR at 128.
// ---------------------------------------------------------------------------
__global__ __launch_bounds__(256, 4) void attn5_kernel(
    const ushort_t* __restrict__ q, const ushort_t* __restrict__ kk,
    const ushort_t* __restrict__ vt, const float* __restrict__ biasf,
    float* __restrict__ op0, float* __restrict__ opws,
    float* __restrict__ mlbuf, int nsplit)
{
  const int b = blockIdx.y, qt = blockIdx.x, sp = blockIdx.z;
  const int t = threadIdx.x;
  const int wave = t >> 6, lane = t & 63, g = lane >> 4, lq = lane & 15;

  const int TT = N_ / 64;
  const int tile_lo = (sp * TT) / nsplit;
  const int tile_hi = ((sp + 1) * TT) / nsplit;
  const int nit = tile_hi - tile_lo;

  __align__(16) __shared__ ushort_t Kt[2][64 * 64];   // [key][d], 16B-chunk XOR swz
  __align__(16) __shared__ ushort_t Vt[2][64 * 64];   // [d][key], 16B-chunk XOR swz
  __align__(16) __shared__ ushort_t Pw[4][16 * 40];   // per-wave P, 80B rows

  const int qbw = qt * 128 + wave * 32;               // wave's first q (in batch)
  short8 qf[2][2];
  #pragma unroll
  for (int u = 0; u < 2; ++u) {
    const size_t qoff = (size_t)(b * N_ + qbw + u * 16 + lq) * D_;
    qf[u][0] = *(const short8*)&q[qoff + g * 8];
    qf[u][1] = *(const short8*)&q[qoff + 32 + g * 8];
  }
  const float* biasb = biasf + b * N_;

  const short8 ones = {0x3F80, 0x3F80, 0x3F80, 0x3F80,
                       0x3F80, 0x3F80, 0x3F80, 0x3F80};   // bf16 1.0 x8

  float m[2] = {0.f, 0.f};          // finite init; defer-max bounds p <= 2^THR
  f32x4 o[4][2];                    // o[dc][u]: q = qbw + u*16 + 4g+r, d = dc*16+lq
  f32x4 o4[2];                      // l columns
  #pragma unroll
  for (int dc = 0; dc < 4; ++dc) {
    o[dc][0] = f32x4{0.f,0.f,0.f,0.f}; o[dc][1] = f32x4{0.f,0.f,0.f,0.f};
  }
  o4[0] = f32x4{0.f,0.f,0.f,0.f}; o4[1] = f32x4{0.f,0.f,0.f,0.f};

  const int r0 = t >> 3, j0 = t & 7;   // staging: rows 0..31 and 32..63
  const int r1 = 32 + r0;
  uint4 k0, k1, v0, v1;

  auto stage_load = [&](int tile) {
    const int jb = (tile_lo + tile) * 64;
    const ushort_t* kbase = kk + (size_t)(b * N_ + jb) * D_;
    k0 = *(const uint4*)&kbase[(size_t)r0 * D_ + j0 * 8];
    k1 = *(const uint4*)&kbase[(size_t)r1 * D_ + j0 * 8];
    const ushort_t* vbase = vt + (size_t)b * D_ * N_ + jb;
    v0 = *(const uint4*)&vbase[(size_t)r0 * N_ + j0 * 8];
    v1 = *(const uint4*)&vbase[(size_t)r1 * N_ + j0 * 8];
  };
  auto stage_write = [&](int bufi) {
    *(uint4*)&Kt[bufi][r0 * 64 + ((j0 ^ (r0 & 7)) * 8)] = k0;
    *(uint4*)&Kt[bufi][r1 * 64 + ((j0 ^ (r1 & 7)) * 8)] = k1;
    *(uint4*)&Vt[bufi][r0 * 64 + ((j0 ^ (r0 & 7)) * 8)] = v0;
    *(uint4*)&Vt[bufi][r1 * 64 + ((j0 ^ (r1 & 7)) * 8)] = v1;
  };

  stage_load(0);
  stage_write(0);
  __syncthreads();

  for (int it = 0; it < nit; ++it) {
    const int bufi = it & 1;
    const int jb = (tile_lo + it) * 64;
    const bool more = (it + 1 < nit);
    if (more) stage_load(it + 1);      // VMEM in flight across compute (T14)

    // bias for the tile's 16 keys/lane (key-indexed; shared by both u)
    float4 bf0 = *(const float4*)&biasb[jb + 0 * 16 + 4 * g];
    float4 bf1 = *(const float4*)&biasb[jb + 1 * 16 + 4 * g];
    float4 bf2 = *(const float4*)&biasb[jb + 2 * 16 + 4 * g];
    float4 bf3 = *(const float4*)&biasb[jb + 3 * 16 + 4 * g];

    // ---- QK^T: each K fragment read once, feeds both q-column blocks ----
    f32x4 st[4][2];
    #pragma unroll
    for (int kc = 0; kc < 4; ++kc) {
      st[kc][0] = f32x4{0.f,0.f,0.f,0.f}; st[kc][1] = f32x4{0.f,0.f,0.f,0.f};
    }
    __builtin_amdgcn_s_setprio(1);
    #pragma unroll
    for (int kc = 0; kc < 4; ++kc) {
      const int row = kc * 16 + lq, sw = row & 7;
      short8 a0 = *(const short8*)&Kt[bufi][row * 64 + ((g ^ sw) * 8)];
      short8 a1 = *(const short8*)&Kt[bufi][row * 64 + (((4 + g) ^ sw) * 8)];
      st[kc][0] = __builtin_amdgcn_mfma_f32_16x16x32_bf16(a0, qf[0][0], st[kc][0], 0, 0, 0);
      st[kc][0] = __builtin_amdgcn_mfma_f32_16x16x32_bf16(a1, qf[0][1], st[kc][0], 0, 0, 0);
      st[kc][1] = __builtin_amdgcn_mfma_f32_16x16x32_bf16(a0, qf[1][0], st[kc][1], 0, 0, 0);
      st[kc][1] = __builtin_amdgcn_mfma_f32_16x16x32_bf16(a1, qf[1][1], st[kc][1], 0, 0, 0);
    }
    __builtin_amdgcn_s_setprio(0);

    // ---- softmax per q-column block (lane owns q = u*16+lq, 16 keys) ----
    unsigned pw[2][8];
    #pragma unroll
    for (int u = 0; u < 2; ++u) {
      float sv[16];
      #pragma unroll
      for (int kc = 0; kc < 4; ++kc) {
        const float4 bf = (kc == 0 ? bf0 : kc == 1 ? bf1 : kc == 2 ? bf2 : bf3);
        sv[kc * 4 + 0] = fmaf(st[kc][u][0], S2LOG, bf.x);
        sv[kc * 4 + 1] = fmaf(st[kc][u][1], S2LOG, bf.y);
        sv[kc * 4 + 2] = fmaf(st[kc][u][2], S2LOG, bf.z);
        sv[kc * 4 + 3] = fmaf(st[kc][u][3], S2LOG, bf.w);
      }
      if (jb == (qbw & ~63)) {         // wave-uniform diagonal tile
        const int dref = qbw + u * 16 + lq - jb - 4 * g;
        #pragma unroll
        for (int kc = 0; kc < 4; ++kc)
          #pragma unroll
          for (int r = 0; r < 4; ++r)
            sv[kc * 4 + r] = (16 * kc + r == dref) ? BIGNEG : sv[kc * 4 + r];
      }
      float a0m = fmaxf(fmaxf(sv[0], sv[1]), sv[2]);
      float a1m = fmaxf(fmaxf(sv[3], sv[4]), sv[5]);
      float a2m = fmaxf(fmaxf(sv[6], sv[7]), sv[8]);
      float a3m = fmaxf(fmaxf(sv[9], sv[10]), sv[11]);
      float a4m = fmaxf(fmaxf(sv[12], sv[13]), sv[14]);
      float tm = fmaxf(fmaxf(fmaxf(a0m, a1m), a2m),
                       fmaxf(fmaxf(a3m, a4m), sv[15]));
      tm = fmaxf(tm, __shfl_xor(tm, 16, 64));
      tm = fmaxf(tm, __shfl_xor(tm, 32, 64));

      if (!__all(tm - m[u] <= THR)) {
        const float mnew = fmaxf(m[u], tm);
        const float corr = exp2_fast(m[u] - mnew);
        const float c0 = __shfl(corr, g * 4 + 0, 64);
        const float c1 = __shfl(corr, g * 4 + 1, 64);
        const float c2 = __shfl(corr, g * 4 + 2, 64);
        const float c3 = __shfl(corr, g * 4 + 3, 64);
        #pragma unroll
        for (int dc = 0; dc < 4; ++dc) {
          o[dc][u][0] *= c0; o[dc][u][1] *= c1; o[dc][u][2] *= c2; o[dc][u][3] *= c3;
        }
        o4[u][0] *= c0; o4[u][1] *= c1; o4[u][2] *= c2; o4[u][3] *= c3;
        m[u] = mnew;
      }

      #pragma unroll
      for (int h = 0; h < 8; ++h) {
        float pa = exp2_fast(sv[2 * h] - m[u]);
        float pb = exp2_fast(sv[2 * h + 1] - m[u]);
        pw[u][h] = cvt_pk_bf16(pa, pb);
      }
    }

    // ---- PV: V fragments read once per kchunk, feed both u ----
    __builtin_amdgcn_s_setprio(1);
    #pragma unroll
    for (int kc2 = 0; kc2 < 2; ++kc2) {
      short8 vv[4];
      #pragma unroll
      for (int dc = 0; dc < 4; ++dc) {
        const int row = dc * 16 + lq, sw = row & 7;
        vv[dc] = *(const short8*)&Vt[bufi][row * 64 + (((kc2 * 4 + g) ^ sw) * 8)];
      }
      #pragma unroll
      for (int u = 0; u < 2; ++u) {
        uint2 w0; w0.x = pw[u][kc2 * 4 + 0]; w0.y = pw[u][kc2 * 4 + 1];
        uint2 w1; w1.x = pw[u][kc2 * 4 + 2]; w1.y = pw[u][kc2 * 4 + 3];
        *(uint2*)&Pw[wave][lq * 40 + 4 * g]      = w0;   // dword cols 2g,2g+1
        *(uint2*)&Pw[wave][lq * 40 + 16 + 4 * g] = w1;   // dword cols 8+2g,+1
        asm volatile("s_waitcnt lgkmcnt(0)" ::: "memory");
        __builtin_amdgcn_sched_barrier(0);
        short8 pf = *(const short8*)&Pw[wave][lq * 40 + 8 * g];
        #pragma unroll
        for (int dc = 0; dc < 4; ++dc)
          o[dc][u] = __builtin_amdgcn_mfma_f32_16x16x32_bf16(pf, vv[dc], o[dc][u], 0, 0, 0);
        o4[u] = __builtin_amdgcn_mfma_f32_16x16x32_bf16(pf, ones, o4[u], 0, 0, 0);
      }
    }
    __builtin_amdgcn_s_setprio(0);

    if (more) stage_write(bufi ^ 1);   // compiler inserts vmcnt before ds_write
    __syncthreads();
  }

  // ---- epilogue: unnormalized O' + (m, l) ----
  float* obase = (sp == 0 ? op0 : opws + (size_t)(sp - 1) * (B_ * N_) * D_)
               + ((size_t)(b * N_) + qbw) * D_;
  #pragma unroll
  for (int u = 0; u < 2; ++u) {
    #pragma unroll
    for (int dc = 0; dc < 4; ++dc) {
      #pragma unroll
      for (int r = 0; r < 4; ++r)
        obase[(size_t)(u * 16 + g * 4 + r) * D_ + dc * 16 + lq] = o[dc][u][r];
    }
  }
  float* mlb = mlbuf + (size_t)sp * (B_ * N_) * 2 + (size_t)(b * N_) * 2;
  #pragma unroll
  for (int u = 0; u < 2; ++u) {
    if (g == 0) mlb[(qbw + u * 16 + lq) * 2 + 0] = m[u];
    if (lq == 0) {
      #pragma unroll
      for (int r = 0; r < 4; ++r)
        mlb[(qbw + u * 16 + 4 * g + r) * 2 + 1] = o4[u][r];
    }
  }
}

// ---------------------------------------------------------------------------
// Merge splits; dead q-rows get the reference's uniform mean over all V.
// ---------------------------------------------------------------------------
__global__ __launch_bounds__(256) void merge_kernel(
    const float* __restrict__ op0, const float* __restrict__ opws,
    const float* __restrict__ mlbuf, const int* __restrict__ mask,
    const float* __restrict__ vmean, float* __restrict__ out, int nsplit)
{
  const int t = threadIdx.x;
  const int qrow = blockIdx.x * 16 + (t >> 4);
  const int d = (t & 15) * 4;
  const int b = qrow >> 12;

  if (!mask[qrow]) {
    *(float4*)&out[(size_t)qrow * D_ + d] = *(const float4*)&vmean[b * D_ + d];
    return;
  }

  float M = -INFINITY;
  for (int s = 0; s < nsplit; ++s)
    M = fmaxf(M, mlbuf[((size_t)s * (B_ * N_) + qrow) * 2]);

  float L = 0.f;
  float ax = 0.f, ay = 0.f, az = 0.f, aw = 0.f;
  for (int s = 0; s < nsplit; ++s) {
    const float* mlp = &mlbuf[((size_t)s * (B_ * N_) + qrow) * 2];
    const float w = exp2_fast(mlp[0] - M);
    L += mlp[1] * w;
    const float* ob = (s == 0) ? op0 : opws + (size_t)(s - 1) * (B_ * N_) * D_;
    float4 ov = *(const float4*)&ob[(size_t)qrow * D_ + d];
    ax += ov.x * w; ay += ov.y * w; az += ov.z * w; aw += ov.w * w;
  }
  const float inv = 1.f / L;
  float4 res; res.x = ax * inv; res.y = ay * inv; res.z = az * inv; res.w = aw * inv;
  *(float4*)&out[(size_t)qrow * D_ + d] = res;
}

// ---------------------------------------------------------------------------
extern "C" void kernel_launch(void* const* d_in, const int* in_sizes, int n_in,
                              void* d_out, int out_size, void* d_ws, size_t ws_size,
                              hipStream_t stream) {
  (void)in_sizes; (void)n_in; (void)out_size;
  const float* Qv = (const float*)d_in[0];
  const float* Kv = (const float*)d_in[1];
  const float* Vv = (const float*)d_in[2];
  const int* mask = (const int*)d_in[3];
  const float* Wq = (const float*)d_in[4];
  const float* Wk = (const float*)d_in[5];
  const float* Wv = (const float*)d_in[6];
  float* out = (float*)d_out;

  ushort_t* qb_ = (ushort_t*)d_ws;                         // [B*N][64] bf16
  ushort_t* kb_ = qb_ + (size_t)B_ * N_ * D_;              // [B*N][64] bf16
  ushort_t* vtb = kb_ + (size_t)B_ * N_ * D_;              // [B][64][N] bf16
  float* biasf  = (float*)(vtb + (size_t)B_ * N_ * D_);    // [B*N] f32
  float* vmean  = biasf + (size_t)B_ * N_;                 // [B][64] f32
  float* mlbuf  = vmean + (size_t)B_ * D_;                 // [8][B*N][2] f32 max
  float* opws   = mlbuf + (size_t)8 * B_ * N_ * 2;         // (nsplit-1) x [B*N][64] f32
  const size_t fixed_bytes = (size_t)((char*)opws - (char*)d_ws);
  const size_t slice_bytes = (size_t)B_ * N_ * D_ * sizeof(float);

  int nsplit = 1;
  if      (ws_size >= fixed_bytes + 7 * slice_bytes) nsplit = 8;
  else if (ws_size >= fixed_bytes + 3 * slice_bytes) nsplit = 4;
  else if (ws_size >= fixed_bytes + 1 * slice_bytes) nsplit = 2;

  proj_kernel<<<dim3(256, 3), dim3(256), 0, stream>>>(
      Qv, Kv, Vv, Wq, Wk, Wv, mask, qb_, kb_, vtb, biasf);
  vmean_kernel<<<dim3(64), dim3(256), 0, stream>>>(vtb, vmean);
  attn5_kernel<<<dim3(N_ / 128, B_, nsplit), dim3(256), 0, stream>>>(
      qb_, kb_, vtb, biasf, out, opws, mlbuf, nsplit);
  merge_kernel<<<dim3(B_ * N_ / 16), dim3(256), 0, stream>>>(
      out, opws, mlbuf, mask, vmean, out, nsplit);
}

// Round 6
// 58.235 us; speedup vs baseline: 2.0861x; 1.7620x over previous
//
#include <hip/hip_runtime.h>

typedef __attribute__((ext_vector_type(8))) short short8;
typedef __attribute__((ext_vector_type(4))) float f32x4;
typedef unsigned short ushort_t;

#define B_ 4
#define N_ 4096
#define E_ 256
#define D_ 64
#define S2LOG 0.1803368801111204f   // (1/sqrt(64)) * log2(e)
#define BIGNEG (-1e30f)
#define THR 8.0f                    // defer-max threshold (log2 units): p <= 256

static __device__ __forceinline__ unsigned short f2bf(float f) {
  union { float f; unsigned int u; } v; v.f = f;
  return (unsigned short)((v.u + 0x7fffu + ((v.u >> 16) & 1u)) >> 16);  // RNE
}
static __device__ __forceinline__ float bf2f(unsigned short h) {
  union { unsigned u; float f; } c; c.u = ((unsigned)h) << 16; return c.f;
}
static __device__ __forceinline__ float exp2_fast(float x) {
  float r; asm("v_exp_f32 %0, %1" : "=v"(r) : "v"(x)); return r;
}
static __device__ __forceinline__ unsigned cvt_pk_bf16(float lo, float hi) {
  unsigned r; asm("v_cvt_pk_bf16_f32 %0, %1, %2" : "=v"(r) : "v"(lo), "v"(hi));
  return r;
}

// ---------------------------------------------------------------------------
// Projection: out = X @ W^T  (X:[B*N,256] f32, W:[64,256] f32) -> bf16
// p=0: q [B*N][64] (+ mask->bias fold); p=1: k [B*N][64]; p=2: vT [B][64][N]
// ---------------------------------------------------------------------------
__global__ __launch_bounds__(256) void proj_kernel(
    const float* __restrict__ Qv, const float* __restrict__ Kv,
    const float* __restrict__ Vv, const float* __restrict__ Wq,
    const float* __restrict__ Wk, const float* __restrict__ Wv,
    const int* __restrict__ mask,
    unsigned short* __restrict__ qo, unsigned short* __restrict__ ko,
    unsigned short* __restrict__ vto, float* __restrict__ biasf)
{
  const int p  = blockIdx.y;
  const int rb = blockIdx.x;
  const int t  = threadIdx.x;

  __align__(16) __shared__ unsigned short Xl[64 * 264];
  __align__(16) __shared__ unsigned short Wl[64 * 264];

  const float* xsrc = (p == 0 ? Qv : (p == 1 ? Kv : Vv)) + (size_t)rb * 64 * E_;
  const float* wsrc = (p == 0 ? Wq : (p == 1 ? Wk : Wv));

  if (p == 0 && t < 64) biasf[rb * 64 + t] = mask[rb * 64 + t] ? 0.f : BIGNEG;

  #pragma unroll
  for (int it = 0; it < 8; ++it) {
    int idx = it * 2048 + t * 8;
    int row = idx >> 8, col = idx & 255;
    float4 a0 = *(const float4*)(xsrc + idx);
    float4 a1 = *(const float4*)(xsrc + idx + 4);
    uint4 wx;
    wx.x = (unsigned)f2bf(a0.x) | ((unsigned)f2bf(a0.y) << 16);
    wx.y = (unsigned)f2bf(a0.z) | ((unsigned)f2bf(a0.w) << 16);
    wx.z = (unsigned)f2bf(a1.x) | ((unsigned)f2bf(a1.y) << 16);
    wx.w = (unsigned)f2bf(a1.z) | ((unsigned)f2bf(a1.w) << 16);
    *(uint4*)&Xl[row * 264 + col] = wx;
    float4 b0 = *(const float4*)(wsrc + idx);
    float4 b1 = *(const float4*)(wsrc + idx + 4);
    uint4 ww;
    ww.x = (unsigned)f2bf(b0.x) | ((unsigned)f2bf(b0.y) << 16);
    ww.y = (unsigned)f2bf(b0.z) | ((unsigned)f2bf(b0.w) << 16);
    ww.z = (unsigned)f2bf(b1.x) | ((unsigned)f2bf(b1.y) << 16);
    ww.w = (unsigned)f2bf(b1.z) | ((unsigned)f2bf(b1.w) << 16);
    *(uint4*)&Wl[row * 264 + col] = ww;
  }
  __syncthreads();

  const int wave = t >> 6, lane = t & 63, g = lane >> 4, lq = lane & 15;
  const unsigned short* TA = (p == 2) ? Wl : Xl;
  const unsigned short* TB = (p == 2) ? Xl : Wl;

  f32x4 acc0 = {0.f,0.f,0.f,0.f}, acc1 = acc0, acc2 = acc0, acc3 = acc0;
  #pragma unroll
  for (int kc = 0; kc < 8; ++kc) {
    short8 af = *(const short8*)&TA[(wave * 16 + lq) * 264 + kc * 32 + g * 8];
    short8 b0 = *(const short8*)&TB[(0 * 16 + lq) * 264 + kc * 32 + g * 8];
    acc0 = __builtin_amdgcn_mfma_f32_16x16x32_bf16(af, b0, acc0, 0, 0, 0);
    short8 b1 = *(const short8*)&TB[(1 * 16 + lq) * 264 + kc * 32 + g * 8];
    acc1 = __builtin_amdgcn_mfma_f32_16x16x32_bf16(af, b1, acc1, 0, 0, 0);
    short8 b2 = *(const short8*)&TB[(2 * 16 + lq) * 264 + kc * 32 + g * 8];
    acc2 = __builtin_amdgcn_mfma_f32_16x16x32_bf16(af, b2, acc2, 0, 0, 0);
    short8 b3 = *(const short8*)&TB[(3 * 16 + lq) * 264 + kc * 32 + g * 8];
    acc3 = __builtin_amdgcn_mfma_f32_16x16x32_bf16(af, b3, acc3, 0, 0, 0);
  }

  if (p < 2) {
    unsigned short* dst = (p == 0 ? qo : ko);
    #pragma unroll
    for (int c = 0; c < 4; ++c) {
      const f32x4 ac = (c == 0 ? acc0 : c == 1 ? acc1 : c == 2 ? acc2 : acc3);
      #pragma unroll
      for (int r = 0; r < 4; ++r) {
        int n = rb * 64 + wave * 16 + g * 4 + r;
        dst[(size_t)n * D_ + c * 16 + lq] = f2bf(ac[r]);
      }
    }
  } else {
    int bb = (rb * 64) >> 12;
    #pragma unroll
    for (int c = 0; c < 4; ++c) {
      const f32x4 ac = (c == 0 ? acc0 : c == 1 ? acc1 : c == 2 ? acc2 : acc3);
      #pragma unroll
      for (int r = 0; r < 4; ++r) {
        int d = wave * 16 + g * 4 + r;
        int n = (rb * 64 + c * 16 + lq) & (N_ - 1);
        vto[((size_t)bb * D_ + d) * N_ + n] = f2bf(ac[r]);
      }
    }
  }
}

// ---------------------------------------------------------------------------
// vmean[b][d] = (1/N) sum_n v[b][n][d].  64 blocks x 4 waves, coalesced.
// ---------------------------------------------------------------------------
__global__ __launch_bounds__(256) void vmean_kernel(
    const ushort_t* __restrict__ vt, float* __restrict__ vmean)
{
  const int t = threadIdx.x, wave = t >> 6, lane = t & 63;
  const int idx = blockIdx.x * 4 + wave;          // (b*64 + d) in [0,256)
  const ushort_t* row = vt + (size_t)idx * N_;
  float s = 0.f;
  #pragma unroll
  for (int i = 0; i < 8; ++i) {
    short8 v = *(const short8*)&row[(i * 64 + lane) * 8];
    #pragma unroll
    for (int j = 0; j < 8; ++j) s += bf2f((unsigned short)v[j]);
  }
  #pragma unroll
  for (int off = 1; off < 64; off <<= 1) s += __shfl_xor(s, off, 64);
  if (lane == 0) vmean[idx] = s * (1.f / N_);
}

// ---------------------------------------------------------------------------
// Flash attention, KV-split. 8 waves x 16 q = 128 q/block; key tile 64;
// double-buffered swizzled K/V LDS shared by 8 waves (amortizes staging);
// 1 barrier/tile; single P-bounce/tile (stride-72 rows, 2-way banks);
// log2-domain softmax + defer-max; row-sum l via MFMA against ones.
// LDS = 51.7 KB -> 3 blocks/CU -> 24 waves/CU ceiling.
// ---------------------------------------------------------------------------
__global__ __launch_bounds__(512, 4) void attn6_kernel(
    const ushort_t* __restrict__ q, const ushort_t* __restrict__ kk,
    const ushort_t* __restrict__ vt, const float* __restrict__ biasf,
    float* __restrict__ op0, float* __restrict__ opws,
    float* __restrict__ mlbuf, int nsplit)
{
  const int b = blockIdx.y, qt = blockIdx.x, sp = blockIdx.z;
  const int t = threadIdx.x;
  const int wave = t >> 6, lane = t & 63, g = lane >> 4, lq = lane & 15;

  const int TT = N_ / 64;
  const int tile_lo = (sp * TT) / nsplit;
  const int tile_hi = ((sp + 1) * TT) / nsplit;
  const int nit = tile_hi - tile_lo;

  __align__(16) __shared__ ushort_t Kt[2][64 * 64];   // [key][d], 16B-chunk XOR swz
  __align__(16) __shared__ ushort_t Vt[2][64 * 64];   // [d][key], 16B-chunk XOR swz
  __shared__ float biasL[2][64];
  __align__(16) __shared__ ushort_t Pl[8][16 * 72];   // per-wave P bounce, 144B rows

  const int qbase = qt * 128 + wave * 16;             // wave's q block (in batch)
  const int qrow_b = qbase + lq;
  const size_t qoff = (size_t)(b * N_ + qrow_b) * D_;
  short8 qf0 = *(const short8*)&q[qoff + g * 8];
  short8 qf1 = *(const short8*)&q[qoff + 32 + g * 8];

  const short8 ones = {0x3F80, 0x3F80, 0x3F80, 0x3F80,
                       0x3F80, 0x3F80, 0x3F80, 0x3F80};   // bf16 1.0 x8

  float m = 0.f;                    // finite init; defer-max bounds p <= 2^THR
  f32x4 o[4];                       // O' accum: q = 4g+r, d = dc*16+lq
  f32x4 o4;                         // l column
  #pragma unroll
  for (int i = 0; i < 4; ++i) o[i] = f32x4{0.f, 0.f, 0.f, 0.f};
  o4 = f32x4{0.f, 0.f, 0.f, 0.f};

  // staging: 512 threads cover one 64x64 bf16 tile per buffer in 1 chunk each
  const int r_ = t >> 3, j_ = t & 7;
  uint4 kreg, vreg; float breg = 0.f;

  auto stage_load = [&](int tile) {
    const int jb = (tile_lo + tile) * 64;
    kreg = *(const uint4*)&kk[(size_t)(b * N_ + jb + r_) * D_ + j_ * 8];
    vreg = *(const uint4*)&vt[((size_t)b * D_ + r_) * N_ + jb + j_ * 8];
    if (t < 64) breg = biasf[b * N_ + jb + t];
  };
  auto stage_write = [&](int bufi) {
    *(uint4*)&Kt[bufi][r_ * 64 + ((j_ ^ (r_ & 7)) * 8)] = kreg;
    *(uint4*)&Vt[bufi][r_ * 64 + ((j_ ^ (r_ & 7)) * 8)] = vreg;
    if (t < 64) biasL[bufi][t] = breg;
  };

  stage_load(0);
  stage_write(0);
  __syncthreads();

  for (int it = 0; it < nit; ++it) {
    const int bufi = it & 1;
    const int jb = (tile_lo + it) * 64;
    const bool more = (it + 1 < nit);
    if (more) stage_load(it + 1);      // VMEM in flight across compute (T14)

    // ---- QK^T (swapped: C rows = keys, cols = q) ----
    f32x4 st[4];
    #pragma unroll
    for (int kc = 0; kc < 4; ++kc) st[kc] = f32x4{0.f, 0.f, 0.f, 0.f};
    __builtin_amdgcn_s_setprio(1);
    #pragma unroll
    for (int kc = 0; kc < 4; ++kc) {
      const int row = kc * 16 + lq, sw = row & 7;
      short8 a0 = *(const short8*)&Kt[bufi][row * 64 + ((g ^ sw) * 8)];
      st[kc] = __builtin_amdgcn_mfma_f32_16x16x32_bf16(a0, qf0, st[kc], 0, 0, 0);
      short8 a1 = *(const short8*)&Kt[bufi][row * 64 + (((4 + g) ^ sw) * 8)];
      st[kc] = __builtin_amdgcn_mfma_f32_16x16x32_bf16(a1, qf1, st[kc], 0, 0, 0);
    }
    __builtin_amdgcn_s_setprio(0);

    // ---- scores in log2 domain (bias from LDS, broadcast reads) ----
    float sv[16];
    #pragma unroll
    for (int kc = 0; kc < 4; ++kc) {
      const float4 bf = *(const float4*)&biasL[bufi][kc * 16 + 4 * g];
      sv[kc * 4 + 0] = fmaf(st[kc][0], S2LOG, bf.x);
      sv[kc * 4 + 1] = fmaf(st[kc][1], S2LOG, bf.y);
      sv[kc * 4 + 2] = fmaf(st[kc][2], S2LOG, bf.z);
      sv[kc * 4 + 3] = fmaf(st[kc][3], S2LOG, bf.w);
    }
    if (jb == (qbase & ~63)) {         // wave-uniform diagonal tile
      const int dref = qrow_b - jb - 4 * g;
      #pragma unroll
      for (int kc = 0; kc < 4; ++kc)
        #pragma unroll
        for (int r = 0; r < 4; ++r)
          sv[kc * 4 + r] = (16 * kc + r == dref) ? BIGNEG : sv[kc * 4 + r];
    }

    // ---- row max ----
    float a0m = fmaxf(fmaxf(sv[0], sv[1]), sv[2]);
    float a1m = fmaxf(fmaxf(sv[3], sv[4]), sv[5]);
    float a2m = fmaxf(fmaxf(sv[6], sv[7]), sv[8]);
    float a3m = fmaxf(fmaxf(sv[9], sv[10]), sv[11]);
    float a4m = fmaxf(fmaxf(sv[12], sv[13]), sv[14]);
    float tm = fmaxf(fmaxf(fmaxf(a0m, a1m), a2m),
                     fmaxf(fmaxf(a3m, a4m), sv[15]));
    tm = fmaxf(tm, __shfl_xor(tm, 16, 64));
    tm = fmaxf(tm, __shfl_xor(tm, 32, 64));

    // ---- defer-max rescale (rare) ----
    if (!__all(tm - m <= THR)) {
      const float mnew = fmaxf(m, tm);
      const float corr = exp2_fast(m - mnew);
      const float c0 = __shfl(corr, g * 4 + 0, 64);
      const float c1 = __shfl(corr, g * 4 + 1, 64);
      const float c2 = __shfl(corr, g * 4 + 2, 64);
      const float c3 = __shfl(corr, g * 4 + 3, 64);
      #pragma unroll
      for (int dc = 0; dc < 4; ++dc) {
        o[dc][0] *= c0; o[dc][1] *= c1; o[dc][2] *= c2; o[dc][3] *= c3;
      }
      o4[0] *= c0; o4[1] *= c1; o4[2] *= c2; o4[3] *= c3;
      m = mnew;
    }

    // ---- P = exp2(sv - m), pack bf16 ----
    unsigned pw[8];
    #pragma unroll
    for (int h = 0; h < 8; ++h) {
      float pa = exp2_fast(sv[2 * h] - m);
      float pb = exp2_fast(sv[2 * h + 1] - m);
      pw[h] = cvt_pk_bf16(pa, pb);
    }

    // ---- single P bounce (per-wave rows, 144B stride = 2-way banks) ----
    #pragma unroll
    for (int kc = 0; kc < 4; ++kc) {
      uint2 w; w.x = pw[kc * 2]; w.y = pw[kc * 2 + 1];
      *(uint2*)&Pl[wave][lq * 72 + kc * 16 + 4 * g] = w;
    }
    asm volatile("s_waitcnt lgkmcnt(0)" ::: "memory");
    __builtin_amdgcn_sched_barrier(0);
    short8 pf0 = *(const short8*)&Pl[wave][lq * 72 + g * 8];
    short8 pf1 = *(const short8*)&Pl[wave][lq * 72 + 32 + g * 8];

    // ---- PV + ones-column (row-sum l) ----
    __builtin_amdgcn_s_setprio(1);
    #pragma unroll
    for (int dc = 0; dc < 4; ++dc) {
      const int row = dc * 16 + lq, sw = row & 7;
      short8 vv0 = *(const short8*)&Vt[bufi][row * 64 + ((g ^ sw) * 8)];
      o[dc] = __builtin_amdgcn_mfma_f32_16x16x32_bf16(pf0, vv0, o[dc], 0, 0, 0);
      short8 vv1 = *(const short8*)&Vt[bufi][row * 64 + (((4 + g) ^ sw) * 8)];
      o[dc] = __builtin_amdgcn_mfma_f32_16x16x32_bf16(pf1, vv1, o[dc], 0, 0, 0);
    }
    o4 = __builtin_amdgcn_mfma_f32_16x16x32_bf16(pf0, ones, o4, 0, 0, 0);
    o4 = __builtin_amdgcn_mfma_f32_16x16x32_bf16(pf1, ones, o4, 0, 0, 0);
    __builtin_amdgcn_s_setprio(0);

    if (more) stage_write(bufi ^ 1);   // vmcnt inserted by compiler
    __syncthreads();                   // separates buf^1 writes from reads
  }

  // ---- epilogue: unnormalized O' + (m, l) ----
  float* obase = (sp == 0 ? op0 : opws + (size_t)(sp - 1) * (B_ * N_) * D_)
               + ((size_t)(b * N_) + qbase) * D_;
  #pragma unroll
  for (int dc = 0; dc < 4; ++dc) {
    #pragma unroll
    for (int r = 0; r < 4; ++r)
      obase[(size_t)(g * 4 + r) * D_ + dc * 16 + lq] = o[dc][r];
  }
  float* mlb = mlbuf + (size_t)sp * (B_ * N_) * 2 + (size_t)(b * N_) * 2;
  if (g == 0) mlb[(qbase + lq) * 2 + 0] = m;
  if (lq == 0) {
    #pragma unroll
    for (int r = 0; r < 4; ++r)
      mlb[(qbase + 4 * g + r) * 2 + 1] = o4[r];
  }
}

// ---------------------------------------------------------------------------
// Merge splits; dead q-rows get the reference's uniform mean over all V.
// ---------------------------------------------------------------------------
__global__ __launch_bounds__(256) void merge_kernel(
    const float* __restrict__ op0, const float* __restrict__ opws,
    const float* __restrict__ mlbuf, const int* __restrict__ mask,
    const float* __restrict__ vmean, float* __restrict__ out, int nsplit)
{
  const int t = threadIdx.x;
  const int qrow = blockIdx.x * 16 + (t >> 4);
  const int d = (t & 15) * 4;
  const int b = qrow >> 12;

  if (!mask[qrow]) {
    *(float4*)&out[(size_t)qrow * D_ + d] = *(const float4*)&vmean[b * D_ + d];
    return;
  }

  float M = -INFINITY;
  for (int s = 0; s < nsplit; ++s)
    M = fmaxf(M, mlbuf[((size_t)s * (B_ * N_) + qrow) * 2]);

  float L = 0.f;
  float ax = 0.f, ay = 0.f, az = 0.f, aw = 0.f;
  for (int s = 0; s < nsplit; ++s) {
    const float* mlp = &mlbuf[((size_t)s * (B_ * N_) + qrow) * 2];
    const float w = exp2_fast(mlp[0] - M);
    L += mlp[1] * w;
    const float* ob = (s == 0) ? op0 : opws + (size_t)(s - 1) * (B_ * N_) * D_;
    float4 ov = *(const float4*)&ob[(size_t)qrow * D_ + d];
    ax += ov.x * w; ay += ov.y * w; az += ov.z * w; aw += ov.w * w;
  }
  const float inv = 1.f / L;
  float4 res; res.x = ax * inv; res.y = ay * inv; res.z = az * inv; res.w = aw * inv;
  *(float4*)&out[(size_t)qrow * D_ + d] = res;
}

// ---------------------------------------------------------------------------
extern "C" void kernel_launch(void* const* d_in, const int* in_sizes, int n_in,
                              void* d_out, int out_size, void* d_ws, size_t ws_size,
                              hipStream_t stream) {
  (void)in_sizes; (void)n_in; (void)out_size;
  const float* Qv = (const float*)d_in[0];
  const float* Kv = (const float*)d_in[1];
  const float* Vv = (const float*)d_in[2];
  const int* mask = (const int*)d_in[3];
  const float* Wq = (const float*)d_in[4];
  const float* Wk = (const float*)d_in[5];
  const float* Wv = (const float*)d_in[6];
  float* out = (float*)d_out;

  ushort_t* qb_ = (ushort_t*)d_ws;                         // [B*N][64] bf16
  ushort_t* kb_ = qb_ + (size_t)B_ * N_ * D_;              // [B*N][64] bf16
  ushort_t* vtb = kb_ + (size_t)B_ * N_ * D_;              // [B][64][N] bf16
  float* biasf  = (float*)(vtb + (size_t)B_ * N_ * D_);    // [B*N] f32
  float* vmean  = biasf + (size_t)B_ * N_;                 // [B][64] f32
  float* mlbuf  = vmean + (size_t)B_ * D_;                 // [8][B*N][2] f32 max
  float* opws   = mlbuf + (size_t)8 * B_ * N_ * 2;         // (nsplit-1) x [B*N][64] f32
  const size_t fixed_bytes = (size_t)((char*)opws - (char*)d_ws);
  const size_t slice_bytes = (size_t)B_ * N_ * D_ * sizeof(float);

  int nsplit = 1;
  if      (ws_size >= fixed_bytes + 5 * slice_bytes) nsplit = 6;
  else if (ws_size >= fixed_bytes + 3 * slice_bytes) nsplit = 4;
  else if (ws_size >= fixed_bytes + 1 * slice_bytes) nsplit = 2;

  proj_kernel<<<dim3(256, 3), dim3(256), 0, stream>>>(
      Qv, Kv, Vv, Wq, Wk, Wv, mask, qb_, kb_, vtb, biasf);
  vmean_kernel<<<dim3(64), dim3(256), 0, stream>>>(vtb, vmean);
  attn6_kernel<<<dim3(N_ / 128, B_, nsplit), dim3(512), 0, stream>>>(
      qb_, kb_, vtb, biasf, out, opws, mlbuf, nsplit);
  merge_kernel<<<dim3(B_ * N_ / 16), dim3(256), 0, stream>>>(
      out, opws, mlbuf, mask, vmean, out, nsplit);
}